// Round 9
// baseline (165.910 us; speedup 1.0000x reference)
//
#include <hip/hip_runtime.h>

#define NPTS 4096
#define N0V  10242
#define EPSV 1e-5f
#define NBLK 256
#define SLOTS 16

__device__ __forceinline__ float fmul(float a,float b){return __fmul_rn(a,b);}
__device__ __forceinline__ float fadd(float a,float b){return __fadd_rn(a,b);}
__device__ __forceinline__ float fsub(float a,float b){return __fsub_rn(a,b);}

// ---------------- prep: pack W^T, pack vertex{x,y,z,v2}, zero acc slots/counters ----------------
__global__ __launch_bounds__(256) void k_init(
    const float* __restrict__ W0, const float* __restrict__ W1, const float* __restrict__ W2,
    const float* __restrict__ vertex,
    float* __restrict__ wt0, float* __restrict__ wt1, float* __restrict__ wt2,
    float* __restrict__ vpk, float* __restrict__ accg, int* __restrict__ cnt)
{
  int t = blockIdx.x * 256 + threadIdx.x;
  if (t < 5120) {                                  // wt0: [40][128] float4 (K=147 zero-padded)
    int c4 = t >> 7, o = t & 127;
    float4 v; float* vv = (float*)&v;
    #pragma unroll
    for (int j = 0; j < 4; j++) { int c = c4*4 + j; vv[j] = (c < 147) ? W0[o*147 + c] : 0.0f; }
    ((float4*)wt0)[t] = v;
  } else if (t < 9216) {                           // wt1: [32][128] float4
    int u = t - 5120; int c4 = u >> 7, o = u & 127;
    float4 v; float* vv = (float*)&v;
    #pragma unroll
    for (int j = 0; j < 4; j++) vv[j] = W1[o*128 + c4*4 + j];
    ((float4*)wt1)[u] = v;
  } else if (t < 13312) {                          // wt2
    int u = t - 9216; int c4 = u >> 7, o = u & 127;
    float4 v; float* vv = (float*)&v;
    #pragma unroll
    for (int j = 0; j < 4; j++) vv[j] = W2[o*128 + c4*4 + j];
    ((float4*)wt2)[u] = v;
  } else if (t < 16384) {                          // zero 3*16*256 floats + counters
    int u = t - 13312;
    ((float4*)accg)[u] = make_float4(0.f,0.f,0.f,0.f);
    if (u < 4) cnt[u] = 0;
  } else if (t < 16384 + N0V) {                    // vpk[m] = {x,y,z,|v|^2}
    int m = t - 16384;
    float x = vertex[3*m], y = vertex[3*m+1], z = vertex[3*m+2];
    float v2 = fadd(fadd(fmul(x,x),fmul(y,y)),fmul(z,z));
    ((float4*)vpk)[m] = make_float4(x,y,z,v2);
  }
}

struct Params {
  const float* orig; const float* proj; const float* vertex; const int* nidx;
  const float* wt0; const float* wt1; const float* wt2; const float* vpk;
  const float* b0; const float* g0; const float* be0;
  const float* b1; const float* g1; const float* be1;
  const float* b2; const float* g2; const float* be2;
  float* accg; int* cnt; float* out;
};

// async DMA: stage nchunks x 1KB of packed weights global->LDS (linear both sides).
__device__ __forceinline__ void stage_w(const float* __restrict__ src, float* dst,
                                        int nchunks, int w, int lane)
{
  for (int i = w; i < nchunks; i += 16){
    const float* g = src + (size_t)(i*64 + lane)*4;
    float* l = dst + (size_t)i*256;                 // wave-uniform LDS base
    __builtin_amdgcn_global_load_lds(
        (const __attribute__((address_space(1))) void*)g,
        (__attribute__((address_space(3))) void*)l,
        16, 0, 0);
  }
}

// dot-product core: thread = (o, rgrp 0..7); 4 rows each; x broadcast from LDS, W per-lane from LDS
template<int K4>
__device__ __forceinline__ void mm_compute(const float4* xs4, int xstr4,
                                           const float4* wlds,
                                           const float* __restrict__ bias,
                                           int o, int rgrp, float* acc)
{
  #pragma unroll
  for (int r=0;r<4;r++) acc[r]=0.0f;
  const float4* wp = wlds + o;
  const float4* xb = xs4 + rgrp*4*xstr4;
  #pragma unroll
  for (int c4=0;c4<K4;c4++){
    float4 wv = wp[c4*128];
    #pragma unroll
    for (int r=0;r<4;r++){
      float4 xv = xb[r*xstr4 + c4];
      acc[r]=fmaf(xv.x,wv.x,acc[r]);
      acc[r]=fmaf(xv.y,wv.y,acc[r]);
      acc[r]=fmaf(xv.z,wv.z,acc[r]);
      acc[r]=fmaf(xv.w,wv.w,acc[r]);
    }
  }
  float bo = bias[o];
  #pragma unroll
  for (int r=0;r<4;r++) acc[r] += bo;
}

// partials -> atomic slots -> RELAXED counter barrier -> ONE acquire fence -> NORMAL cached
// slot reads -> redundant stats -> stS/stB in LDS.
// Correctness chain: (a) slot atomicAdds drained (vmcnt) at the pre-arrival __syncthreads, so
// cnt increment is issued only after this block's adds are globally performed; (b) observing
// cnt==NBLK implies ALL blocks' adds are at the coherence point; (c) the single acquire fence
// invalidates L1/L2 so the subsequent normal loads refetch coherence-point data.
// y-write into LDS and next-layer weight DMA are overlapped under the barrier wait.
__device__ __forceinline__ void layer_stats(const float* acc4, float* bufY,
    float* __restrict__ accL, int* __restrict__ cntp,
    const float* __restrict__ g, const float* __restrict__ be,
    const float* __restrict__ stage_src, float* stage_dst, int stage_chunks,
    float* redp, float* red2, float* stS, float* stB, int t, int blk)
{
  float s1=0.0f, s2=0.0f;
  #pragma unroll
  for (int r=0;r<4;r++){ s1 += acc4[r]; s2 = fmaf(acc4[r],acc4[r],s2); }
  int o = t & 127, rgrp = t >> 7;
  redp[rgrp*128 + o]        = s1;
  redp[1024 + rgrp*128 + o] = s2;
  __syncthreads();                                  // all waves done with mm (and LDS weights)
  if (stage_src) stage_w(stage_src, stage_dst, stage_chunks, t >> 6, t & 63);
  if (t < 256){
    int q = t >> 7, ch = t & 127;
    const float* rp = redp + q*1024 + ch;
    float v = ((rp[0]+rp[128])+(rp[256]+rp[384])) + ((rp[512]+rp[640])+(rp[768]+rp[896]));
    atomicAdd(&accL[(blk & (SLOTS-1))*256 + t], v); // agent-scope, coherence point
  }
  __syncthreads();   // vmcnt(0): this block's atomics (and staging DMA) globally performed
  if (t == 0)
    __hip_atomic_fetch_add(cntp, 1, __ATOMIC_RELAXED, __HIP_MEMORY_SCOPE_AGENT);
  if (bufY){                                        // overlap y-write with other blocks' arrival
    #pragma unroll
    for (int r=0;r<4;r++) bufY[(rgrp*4+r)*132 + o] = acc4[r];
  }
  if (t == 0){
    while (__hip_atomic_load(cntp, __ATOMIC_RELAXED, __HIP_MEMORY_SCOPE_AGENT) < NBLK)
      __builtin_amdgcn_s_sleep(2);
  }
  __syncthreads();
  __builtin_amdgcn_fence(__ATOMIC_ACQUIRE, "agent"); // single L1/L2 inv per block per barrier
  if (t < 256){
    float v = 0.0f;
    #pragma unroll
    for (int s=0;s<SLOTS;s++) v += accL[s*256 + t];  // normal cached loads
    red2[t] = v;
  }
  __syncthreads();
  if (t < 128){
    float S = red2[t], Q = red2[128 + t];
    float mean = S * (1.0f/8192.0f);
    float var  = Q * (1.0f/8192.0f) - mean*mean;
    float inv  = 1.0f / __fsqrt_rn(var + EPSV);
    float sc = g[t]*inv;
    stS[t] = sc;
    stB[t] = be[t] - mean*sc;
  }
  __syncthreads();
}

// in-place affine+relu on [32][132] tile (f4 stride 33, cols 0..127); 1024 threads, 1 f4 each
__device__ __forceinline__ void transform_buf(float* buf, const float* stS, const float* stB, int t)
{
  float4* b4 = (float4*)buf;
  int r = t >> 5, c4 = t & 31;
  float4 v = b4[r*33 + c4];
  int c = c4*4;
  v.x = fmaxf(fmaf(v.x, stS[c  ], stB[c  ]), 0.0f);
  v.y = fmaxf(fmaf(v.y, stS[c+1], stB[c+1]), 0.0f);
  v.z = fmaxf(fmaf(v.z, stS[c+2], stB[c+2]), 0.0f);
  v.w = fmaxf(fmaf(v.w, stS[c+3], stB[c+3]), 0.0f);
  b4[r*33 + c4] = v;
  __syncthreads();
}

__global__ __launch_bounds__(1024) void k_fused(Params p)
{
  extern __shared__ __align__(16) float ldsw[];  // 5120 float4 = 80KB weight buffer
  __shared__ __align__(16) float bufA[32*160];   // x0 [32][160]; later y1/x2 [32][132]
  __shared__ __align__(16) float bufB[32*132];   // y0/x1; later y2
  __shared__ float redp[2048];
  __shared__ float red2[256];
  __shared__ float stS[128];
  __shared__ float stB[128];

  const int t    = threadIdx.x;
  const int blk  = blockIdx.x;
  const int lane = t & 63;
  const int w    = t >> 6;            // wave 0..15
  const int b    = blk >> 7;
  const int n0   = (blk & 127) * 32;
  const int o    = t & 127;
  const int rgrp = t >> 7;            // 0..7 -> rows rgrp*4 .. +3

  // kick off wt0 staging immediately; completes under the feat scan
  stage_w(p.wt0, ldsw, 80, w, lane);

  // ---------------- feat: block's 32 rows -> bufA[row][0..159]; 2 rows per wave ----------------
  {
    float v0x=p.vertex[0], v0y=p.vertex[1], v0z=p.vertex[2];
    float r  = __fsqrt_rn(fadd(fadd(fmul(v0x,v0x),fmul(v0y,v0y)),fmul(v0z,v0z)));
    float rr = fmul(r,r);
    int j0 = p.nidx[0];
    float ax=p.vertex[3*j0], ay=p.vertex[3*j0+1], az=p.vertex[3*j0+2];
    float dx=fsub(v0x,ax), dy=fsub(v0y,ay), dz=fsub(v0z,az);
    float t2 = fadd(fadd(fmul(dx,dx),fmul(dy,dy)),fmul(dz,dz));
    const float4* vp4 = (const float4*)p.vpk;

    int firsts[2]; int hass[2];
    #pragma unroll
    for (int rr_i=0; rr_i<2; rr_i++){
      const int row = w*2 + rr_i;
      const int n = n0 + row;
      const float* ob = p.orig + (b*19)*NPTS + n;
      float x=ob[0], y=ob[NPTS], z=ob[2*NPTS];
      float nrm = __fsqrt_rn(fadd(fadd(fmul(x,x),fmul(y,y)),fmul(z,z)));
      float s = __fdiv_rn(r,nrm);
      float px=fmul(x,s), py=fmul(y,s), pz=fmul(z,s);
      int first=0, has=0;
      for (int c0=0; c0<N0V; c0+=256){           // 4 chunks in flight per iteration
        int m0=c0+lane, m1=m0+64, m2=m0+128, m3=m0+192;
        float4 va = vp4[min(m0, N0V-1)];
        float4 vb = vp4[min(m1, N0V-1)];
        float4 vc = vp4[min(m2, N0V-1)];
        float4 vd = vp4[min(m3, N0V-1)];
        float dta = fadd(fadd(fmul(px,va.x),fmul(py,va.y)),fmul(pz,va.z));
        float dtb = fadd(fadd(fmul(px,vb.x),fmul(py,vb.y)),fmul(pz,vb.z));
        float dtc = fadd(fadd(fmul(px,vc.x),fmul(py,vc.y)),fmul(pz,vc.z));
        float dtd = fadd(fadd(fmul(px,vd.x),fmul(py,vd.y)),fmul(pz,vd.z));
        bool h0 = (m0<N0V) && (fsub(fadd(rr,va.w),fmul(2.0f,dta)) <= t2);
        bool h1 = (m1<N0V) && (fsub(fadd(rr,vb.w),fmul(2.0f,dtb)) <= t2);
        bool h2 = (m2<N0V) && (fsub(fadd(rr,vc.w),fmul(2.0f,dtc)) <= t2);
        bool h3 = (m3<N0V) && (fsub(fadd(rr,vd.w),fmul(2.0f,dtd)) <= t2);
        unsigned long long bal;
        if ((bal=__ballot(h0))){ first=c0     +__builtin_ctzll(bal); has=1; break; }
        if ((bal=__ballot(h1))){ first=c0+ 64+__builtin_ctzll(bal); has=1; break; }
        if ((bal=__ballot(h2))){ first=c0+128+__builtin_ctzll(bal); has=1; break; }
        if ((bal=__ballot(h3))){ first=c0+192+__builtin_ctzll(bal); has=1; break; }
      }
      firsts[rr_i]=first; hass[rr_i]=has;
    }
    const float* pb = p.proj + (long)b*128*N0V;
    #pragma unroll
    for (int rr_i=0; rr_i<2; rr_i++){
      const int row = w*2 + rr_i;
      const int n = n0 + row;
      #pragma unroll
      for (int k=0;k<3;k++){
        int idx = lane + k*64;
        if (idx < 160){
          float v;
          if (idx < 19)        v = p.orig[(b*19+idx)*NPTS + n];
          else if (idx < 147)  v = hass[rr_i] ? pb[(long)(idx-19)*N0V + firsts[rr_i]] : 0.0f;
          else                 v = 0.0f;
          bufA[row*160 + idx] = v;
        }
      }
    }
  }
  __syncthreads();   // feat done AND wt0 staging drained (vmcnt(0) at barrier)

  float acc[4];

  // ---------------- layer 0 ----------------
  mm_compute<40>((const float4*)bufA, 40, (const float4*)ldsw, p.b0, o, rgrp, acc);
  layer_stats(acc, bufB, p.accg,        p.cnt,   p.g0, p.be0, p.wt1, ldsw, 64,
              redp, red2, stS, stB, t, blk);
  transform_buf(bufB, stS, stB, t);

  // ---------------- layer 1 ----------------
  mm_compute<32>((const float4*)bufB, 33, (const float4*)ldsw, p.b1, o, rgrp, acc);
  layer_stats(acc, bufA, p.accg + 4096, p.cnt+1, p.g1, p.be1, p.wt2, ldsw, 64,
              redp, red2, stS, stB, t, blk);
  transform_buf(bufA, stS, stB, t);

  // ---------------- layer 2 ----------------
  mm_compute<32>((const float4*)bufA, 33, (const float4*)ldsw, p.b2, o, rgrp, acc);
  layer_stats(acc, nullptr, p.accg + 8192, p.cnt+2, p.g2, p.be2, nullptr, nullptr, 0,
              redp, red2, stS, stB, t, blk);

  // affine+relu in regs -> LDS -> coalesced transposed store
  {
    float ss = stS[o], sb = stB[o];
    #pragma unroll
    for (int r=0;r<4;r++)
      bufB[(rgrp*4+r)*132 + o] = fmaxf(fmaf(acc[r], ss, sb), 0.0f);
  }
  __syncthreads();
  {
    float* ob = p.out + (long)b*128*NPTS + n0;
    int oo = t >> 3, j = (t & 7) * 4;            // 128 outputs x 32 rows, 1 float4/thread
    float4 v;
    v.x = bufB[(j  )*132 + oo];
    v.y = bufB[(j+1)*132 + oo];
    v.z = bufB[(j+2)*132 + oo];
    v.w = bufB[(j+3)*132 + oo];
    *(float4*)(ob + (long)oo*NPTS + j) = v;
  }
}

extern "C" void kernel_launch(void* const* d_in, const int* in_sizes, int n_in,
                              void* d_out, int out_size, void* d_ws, size_t ws_size,
                              hipStream_t stream)
{
  const float* orig   = (const float*)d_in[0];
  const float* proj   = (const float*)d_in[1];
  const float* vertex = (const float*)d_in[2];
  const int*   nidx   = (const int*)d_in[3];
  const float* W0 = (const float*)d_in[4];
  const float* b0 = (const float*)d_in[5];
  const float* g0 = (const float*)d_in[6];
  const float* be0= (const float*)d_in[7];
  const float* W1 = (const float*)d_in[8];
  const float* b1 = (const float*)d_in[9];
  const float* g1 = (const float*)d_in[10];
  const float* be1= (const float*)d_in[11];
  const float* W2 = (const float*)d_in[12];
  const float* b2 = (const float*)d_in[13];
  const float* g2 = (const float*)d_in[14];
  const float* be2= (const float*)d_in[15];
  float* out = (float*)d_out;

  float* ws   = (float*)d_ws;
  float* accg = ws;                         // 3*16*256 = 12288 floats
  int*   cnt  = (int*)(ws + 12288);         // 4 ints (pad to 16)
  float* wt0  = ws + 12304;                 // 5120 float4 = 20480 floats
  float* wt1  = wt0 + 20480;                // 16384
  float* wt2  = wt1 + 16384;                // 16384
  float* vpk  = wt2 + 16384;                // 10242 float4 = 40968 floats

  static int attr_set = 0;
  if (!attr_set) {
    hipFuncSetAttribute((const void*)k_fused,
                        hipFuncAttributeMaxDynamicSharedMemorySize, 81920);
    attr_set = 1;
  }

  k_init<<<105, 256, 0, stream>>>(W0, W1, W2, vertex, wt0, wt1, wt2, vpk, accg, cnt);

  Params p{orig, proj, vertex, nidx, wt0, wt1, wt2, vpk,
           b0, g0, be0, b1, g1, be1, b2, g2, be2,
           accg, cnt, out};
  void* args[] = {(void*)&p};
  hipLaunchCooperativeKernel((const void*)k_fused, dim3(NBLK), dim3(1024), args, 81920, stream);
}

// Round 10
// 52.961 us; speedup vs baseline: 3.1327x; 3.1327x over previous
//
#include <hip/hip_runtime.h>

#define NPTS 4096
#define N0V  10242
#define EPSV 1e-5f
#define NBLK 256
#define SLOTS 16

typedef unsigned short ushortT;
typedef __attribute__((ext_vector_type(8))) short short8;
typedef __attribute__((ext_vector_type(4))) float f32x4;

__device__ __forceinline__ float fmul(float a,float b){return __fmul_rn(a,b);}
__device__ __forceinline__ float fadd(float a,float b){return __fadd_rn(a,b);}
__device__ __forceinline__ float fsub(float a,float b){return __fsub_rn(a,b);}

__device__ __forceinline__ ushortT f2bf(float x){
  unsigned u = __float_as_uint(x);
  u = (u + 0x7fffu + ((u>>16)&1u)) >> 16;
  return (ushortT)u;
}

// ---------------- prep: pack bf16 W^T [3][128][168], vertex{x,y,z,v2}, zero slots ----------------
__global__ __launch_bounds__(256) void k_init(
    const float* __restrict__ W0, const float* __restrict__ W1, const float* __restrict__ W2,
    const float* __restrict__ vertex,
    ushortT* __restrict__ wpk, float* __restrict__ vpk,
    float* __restrict__ accg, int* __restrict__ cnt)
{
  int t = blockIdx.x*256 + threadIdx.x;
  if (t < 64512){
    int L = t / 21504, u = t - L*21504;
    int o = u / 168, k = u - o*168;
    float v = 0.f;
    if (L == 0)      { if (k < 147) v = W0[o*147 + k]; }
    else if (L == 1) { if (k < 128) v = W1[o*128 + k]; }
    else             { if (k < 128) v = W2[o*128 + k]; }
    wpk[t] = f2bf(v);
  } else if (t < 64512 + 3072){
    ((float4*)accg)[t - 64512] = make_float4(0.f,0.f,0.f,0.f);
    if (t - 64512 < 4) cnt[t - 64512] = 0;
  } else if (t < 64512 + 3072 + N0V){
    int m = t - 64512 - 3072;
    float x = vertex[3*m], y = vertex[3*m+1], z = vertex[3*m+2];
    float v2 = fadd(fadd(fmul(x,x),fmul(y,y)),fmul(z,z));
    ((float4*)vpk)[m] = make_float4(x,y,z,v2);
  }
}

struct Params {
  const float* orig; const float* proj; const float* vertex; const int* nidx;
  const ushortT* wpk; const float* vpk;
  const float* b0; const float* g0; const float* be0;
  const float* b1; const float* g1; const float* be1;
  const float* b2; const float* g2; const float* be2;
  float* accg; int* cnt; float* out;
};

// R8-proven barrier: relaxed counter + relaxed atomic slot reads (NO fences/cache maintenance)
__device__ __forceinline__ void grid_stats(
    float* __restrict__ accL, int* __restrict__ cntp,
    const float* __restrict__ g, const float* __restrict__ be,
    float* red2, float* stS, float* stB, int t)
{
  __syncthreads();                                 // drains vmcnt: slot atomicAdds performed
  if (t == 0){
    __hip_atomic_fetch_add(cntp, 1, __ATOMIC_RELAXED, __HIP_MEMORY_SCOPE_AGENT);
    while (__hip_atomic_load(cntp, __ATOMIC_RELAXED, __HIP_MEMORY_SCOPE_AGENT) < NBLK)
      __builtin_amdgcn_s_sleep(2);
  }
  __syncthreads();
  if (t < 256){
    float v = 0.f;
    #pragma unroll
    for (int s=0;s<SLOTS;s++)
      v += __hip_atomic_load(&accL[s*256 + t], __ATOMIC_RELAXED, __HIP_MEMORY_SCOPE_AGENT);
    red2[t] = v;
  }
  __syncthreads();
  if (t < 128){
    float S = red2[t], Q = red2[128 + t];
    float mean = S * (1.0f/8192.0f);
    float var  = Q * (1.0f/8192.0f) - mean*mean;
    float inv  = 1.0f / __fsqrt_rn(var + EPSV);
    float sc = g[t]*inv;
    stS[t] = sc;
    stB[t] = be[t] - mean*sc;
  }
  __syncthreads();
}

__global__ __launch_bounds__(1024) void k_fused(Params p)
{
  extern __shared__ __align__(16) char ldsw[];     // 129024B: bf16 W [3][128][168]
  __shared__ __align__(16) ushortT xa0[32*168];    // bf16 activation tile A
  __shared__ __align__(16) ushortT xa1[32*168];    // bf16 activation tile B
  __shared__ float red2[256];
  __shared__ float stS[128];
  __shared__ float stB[128];

  const int t    = threadIdx.x;
  const int blk  = blockIdx.x;
  const int lane = t & 63;
  const int w    = t >> 6;            // wave 0..15
  const int b    = blk >> 7;
  const int n0   = (blk & 127) * 32;
  const int li   = lane & 15;         // MFMA col-within-tile / row-within-tile
  const int hi   = lane >> 4;         // 0..3 -> k-offset hi*8; C/D rows hi*4+reg
  const int rt   = w >> 3;            // row tile 0..1 (rows rt*16..+15)
  const int ct   = w & 7;             // col tile 0..7 (cols ct*16..+15)
  const int colg = ct*16 + li;        // this lane's output channel

  // stage all 3 bf16 weight layers into LDS (126 x 1KB chunks); hidden under feat
  {
    const char* src = (const char*)p.wpk;
    for (int i = w; i < 126; i += 16){
      const char* g = src + (size_t)i*1024 + (size_t)lane*16;
      char* l = ldsw + (size_t)i*1024;
      __builtin_amdgcn_global_load_lds(
          (const __attribute__((address_space(1))) void*)g,
          (__attribute__((address_space(3))) void*)l, 16, 0, 0);
    }
  }

  // ---------------- feat: block's 32 rows -> xa0[row][0..159] (bf16); 2 rows/wave ----------------
  {
    float v0x=p.vertex[0], v0y=p.vertex[1], v0z=p.vertex[2];
    float r  = __fsqrt_rn(fadd(fadd(fmul(v0x,v0x),fmul(v0y,v0y)),fmul(v0z,v0z)));
    float rr = fmul(r,r);
    int j0 = p.nidx[0];
    float ax=p.vertex[3*j0], ay=p.vertex[3*j0+1], az=p.vertex[3*j0+2];
    float dx=fsub(v0x,ax), dy=fsub(v0y,ay), dz=fsub(v0z,az);
    float t2 = fadd(fadd(fmul(dx,dx),fmul(dy,dy)),fmul(dz,dz));
    const float4* vp4 = (const float4*)p.vpk;

    int firsts[2]; int hass[2];
    #pragma unroll
    for (int rr_i=0; rr_i<2; rr_i++){
      const int row = w*2 + rr_i;
      const int n = n0 + row;
      const float* ob = p.orig + (b*19)*NPTS + n;
      float x=ob[0], y=ob[NPTS], z=ob[2*NPTS];
      float nrm = __fsqrt_rn(fadd(fadd(fmul(x,x),fmul(y,y)),fmul(z,z)));
      float s = __fdiv_rn(r,nrm);
      float px=fmul(x,s), py=fmul(y,s), pz=fmul(z,s);
      int first=0, has=0;
      for (int c0=0; c0<N0V; c0+=256){
        int m0=c0+lane, m1=m0+64, m2=m0+128, m3=m0+192;
        float4 va = vp4[min(m0, N0V-1)];
        float4 vb = vp4[min(m1, N0V-1)];
        float4 vc = vp4[min(m2, N0V-1)];
        float4 vd = vp4[min(m3, N0V-1)];
        float dta = fadd(fadd(fmul(px,va.x),fmul(py,va.y)),fmul(pz,va.z));
        float dtb = fadd(fadd(fmul(px,vb.x),fmul(py,vb.y)),fmul(pz,vb.z));
        float dtc = fadd(fadd(fmul(px,vc.x),fmul(py,vc.y)),fmul(pz,vc.z));
        float dtd = fadd(fadd(fmul(px,vd.x),fmul(py,vd.y)),fmul(pz,vd.z));
        bool h0 = (m0<N0V) && (fsub(fadd(rr,va.w),fmul(2.0f,dta)) <= t2);
        bool h1 = (m1<N0V) && (fsub(fadd(rr,vb.w),fmul(2.0f,dtb)) <= t2);
        bool h2 = (m2<N0V) && (fsub(fadd(rr,vc.w),fmul(2.0f,dtc)) <= t2);
        bool h3 = (m3<N0V) && (fsub(fadd(rr,vd.w),fmul(2.0f,dtd)) <= t2);
        unsigned long long bal;
        if ((bal=__ballot(h0))){ first=c0     +__builtin_ctzll(bal); has=1; break; }
        if ((bal=__ballot(h1))){ first=c0+ 64+__builtin_ctzll(bal); has=1; break; }
        if ((bal=__ballot(h2))){ first=c0+128+__builtin_ctzll(bal); has=1; break; }
        if ((bal=__ballot(h3))){ first=c0+192+__builtin_ctzll(bal); has=1; break; }
      }
      firsts[rr_i]=first; hass[rr_i]=has;
    }
    const float* pb = p.proj + (long)b*128*N0V;
    #pragma unroll
    for (int rr_i=0; rr_i<2; rr_i++){
      const int row = w*2 + rr_i;
      const int n = n0 + row;
      #pragma unroll
      for (int k=0;k<3;k++){
        int idx = lane + k*64;
        if (idx < 160){
          float v;
          if (idx < 19)        v = p.orig[(b*19+idx)*NPTS + n];
          else if (idx < 147)  v = hass[rr_i] ? pb[(long)(idx-19)*N0V + firsts[rr_i]] : 0.0f;
          else                 v = 0.0f;
          xa0[row*168 + idx] = f2bf(v);
        }
      }
    }
  }
  __syncthreads();   // feat done AND weight staging drained (vmcnt(0) at barrier)

  const ushortT* wb0 = (const ushortT*)ldsw;
  const ushortT* wb1 = wb0 + 21504;
  const ushortT* wb2 = wb1 + 21504;
  f32x4 acc;

  // ================ layer 0: xa0(K=160,pad) x wb0 -> acc ================
  {
    const ushortT* xap = xa0 + (rt*16 + li)*168 + hi*8;
    const ushortT* wbp = wb0 + colg*168 + hi*8;
    acc = (f32x4){0.f,0.f,0.f,0.f};
    #pragma unroll
    for (int s=0;s<5;s++){
      short8 a  = *(const short8*)(xap + s*32);
      short8 bb = *(const short8*)(wbp + s*32);
      acc = __builtin_amdgcn_mfma_f32_16x16x32_bf16(a, bb, acc, 0,0,0);
    }
    float bo = p.b0[colg];
    acc[0]+=bo; acc[1]+=bo; acc[2]+=bo; acc[3]+=bo;
    float s1 = (acc[0]+acc[1])+(acc[2]+acc[3]);
    float s2 = fmaf(acc[0],acc[0],fmaf(acc[1],acc[1],fmaf(acc[2],acc[2],acc[3]*acc[3])));
    s1 += __shfl_xor(s1,16); s1 += __shfl_xor(s1,32);
    s2 += __shfl_xor(s2,16); s2 += __shfl_xor(s2,32);
    if (lane < 16){
      float* sl = p.accg + (blk & (SLOTS-1))*256;
      atomicAdd(&sl[colg], s1);
      atomicAdd(&sl[128 + colg], s2);
    }
    grid_stats(p.accg, p.cnt, p.g0, p.be0, red2, stS, stB, t);
    float ss = stS[colg], sb = stB[colg];
    #pragma unroll
    for (int r=0;r<4;r++){
      int row = rt*16 + hi*4 + r;
      xa1[row*168 + colg] = f2bf(fmaxf(fmaf(acc[r], ss, sb), 0.f));
    }
  }
  __syncthreads();

  // ================ layer 1: xa1(K=128) x wb1 ================
  {
    const ushortT* xap = xa1 + (rt*16 + li)*168 + hi*8;
    const ushortT* wbp = wb1 + colg*168 + hi*8;
    acc = (f32x4){0.f,0.f,0.f,0.f};
    #pragma unroll
    for (int s=0;s<4;s++){
      short8 a  = *(const short8*)(xap + s*32);
      short8 bb = *(const short8*)(wbp + s*32);
      acc = __builtin_amdgcn_mfma_f32_16x16x32_bf16(a, bb, acc, 0,0,0);
    }
    float bo = p.b1[colg];
    acc[0]+=bo; acc[1]+=bo; acc[2]+=bo; acc[3]+=bo;
    float s1 = (acc[0]+acc[1])+(acc[2]+acc[3]);
    float s2 = fmaf(acc[0],acc[0],fmaf(acc[1],acc[1],fmaf(acc[2],acc[2],acc[3]*acc[3])));
    s1 += __shfl_xor(s1,16); s1 += __shfl_xor(s1,32);
    s2 += __shfl_xor(s2,16); s2 += __shfl_xor(s2,32);
    if (lane < 16){
      float* sl = p.accg + 4096 + (blk & (SLOTS-1))*256;
      atomicAdd(&sl[colg], s1);
      atomicAdd(&sl[128 + colg], s2);
    }
    grid_stats(p.accg + 4096, p.cnt+1, p.g1, p.be1, red2, stS, stB, t);
    float ss = stS[colg], sb = stB[colg];
    #pragma unroll
    for (int r=0;r<4;r++){
      int row = rt*16 + hi*4 + r;
      xa0[row*168 + colg] = f2bf(fmaxf(fmaf(acc[r], ss, sb), 0.f));
    }
  }
  __syncthreads();

  // ================ layer 2: xa0(K=128) x wb2 ================
  {
    const ushortT* xap = xa0 + (rt*16 + li)*168 + hi*8;
    const ushortT* wbp = wb2 + colg*168 + hi*8;
    acc = (f32x4){0.f,0.f,0.f,0.f};
    #pragma unroll
    for (int s=0;s<4;s++){
      short8 a  = *(const short8*)(xap + s*32);
      short8 bb = *(const short8*)(wbp + s*32);
      acc = __builtin_amdgcn_mfma_f32_16x16x32_bf16(a, bb, acc, 0,0,0);
    }
    float bo = p.b2[colg];
    acc[0]+=bo; acc[1]+=bo; acc[2]+=bo; acc[3]+=bo;
    float s1 = (acc[0]+acc[1])+(acc[2]+acc[3]);
    float s2 = fmaf(acc[0],acc[0],fmaf(acc[1],acc[1],fmaf(acc[2],acc[2],acc[3]*acc[3])));
    s1 += __shfl_xor(s1,16); s1 += __shfl_xor(s1,32);
    s2 += __shfl_xor(s2,16); s2 += __shfl_xor(s2,32);
    if (lane < 16){
      float* sl = p.accg + 8192 + (blk & (SLOTS-1))*256;
      atomicAdd(&sl[colg], s1);
      atomicAdd(&sl[128 + colg], s2);
    }
    grid_stats(p.accg + 8192, p.cnt+2, p.g2, p.be2, red2, stS, stB, t);
    // final affine+relu in f32 -> LDS tile (alias of dead wb0 region) -> coalesced store
    float* ldsY = (float*)ldsw;   // [32][132] f32 = 16896B < 43008B (wb0, dead after layer 0)
    float ss = stS[colg], sb = stB[colg];
    #pragma unroll
    for (int r=0;r<4;r++){
      int row = rt*16 + hi*4 + r;
      ldsY[row*132 + colg] = fmaxf(fmaf(acc[r], ss, sb), 0.f);
    }
  }
  __syncthreads();
  {
    float* ldsY = (float*)ldsw;
    float* ob = p.out + (long)b*128*NPTS + n0;
    int oo = t >> 3, j = (t & 7) * 4;
    float4 v;
    v.x = ldsY[(j  )*132 + oo];
    v.y = ldsY[(j+1)*132 + oo];
    v.z = ldsY[(j+2)*132 + oo];
    v.w = ldsY[(j+3)*132 + oo];
    *(float4*)(ob + (long)oo*NPTS + j) = v;
  }
}

extern "C" void kernel_launch(void* const* d_in, const int* in_sizes, int n_in,
                              void* d_out, int out_size, void* d_ws, size_t ws_size,
                              hipStream_t stream)
{
  const float* orig   = (const float*)d_in[0];
  const float* proj   = (const float*)d_in[1];
  const float* vertex = (const float*)d_in[2];
  const int*   nidx   = (const int*)d_in[3];
  const float* W0 = (const float*)d_in[4];
  const float* b0 = (const float*)d_in[5];
  const float* g0 = (const float*)d_in[6];
  const float* be0= (const float*)d_in[7];
  const float* W1 = (const float*)d_in[8];
  const float* b1 = (const float*)d_in[9];
  const float* g1 = (const float*)d_in[10];
  const float* be1= (const float*)d_in[11];
  const float* W2 = (const float*)d_in[12];
  const float* b2 = (const float*)d_in[13];
  const float* g2 = (const float*)d_in[14];
  const float* be2= (const float*)d_in[15];
  float* out = (float*)d_out;

  float*   ws   = (float*)d_ws;
  float*   accg = ws;                          // 3*16*256 = 12288 floats
  int*     cnt  = (int*)(ws + 12288);          // 4 ints (16 floats reserved)
  ushortT* wpk  = (ushortT*)(ws + 12304);      // 64512 bf16 = 32256 floats
  float*   vpk  = ws + 12304 + 32256;          // 10242 float4 = 40968 floats

  hipFuncSetAttribute((const void*)k_fused,
                      hipFuncAttributeMaxDynamicSharedMemorySize, 129024);

  k_init<<<305, 256, 0, stream>>>(W0, W1, W2, vertex, wpk, vpk, accg, cnt);

  Params p{orig, proj, vertex, nidx, wpk, vpk,
           b0, g0, be0, b1, g1, be1, b2, g2, be2,
           accg, cnt, out};
  void* args[] = {(void*)&p};
  hipLaunchCooperativeKernel((const void*)k_fused, dim3(NBLK), dim3(1024), args, 129024, stream);
}

// Round 12
// 48.961 us; speedup vs baseline: 3.3886x; 1.0817x over previous
//
#include <hip/hip_runtime.h>

#define NPTS 4096
#define N0V  10242
#define EPSV 1e-5f
#define NBLK 128
#define SLOTS 16

typedef unsigned short ushortT;
typedef __attribute__((ext_vector_type(8))) short short8;
typedef __attribute__((ext_vector_type(4))) float f32x4;

__device__ __forceinline__ float fmul(float a,float b){return __fmul_rn(a,b);}
__device__ __forceinline__ float fadd(float a,float b){return __fadd_rn(a,b);}
__device__ __forceinline__ float fsub(float a,float b){return __fsub_rn(a,b);}

__device__ __forceinline__ ushortT f2bf(float x){
  unsigned u = __float_as_uint(x);
  u = (u + 0x7fffu + ((u>>16)&1u)) >> 16;
  return (ushortT)u;
}

// ===== prep: feat scan+gather (1 row/wave) + bf16 weight pack + zero slots =====
// blocks 0..511: scan rows; 512..566: pack weights; 567: zero accg/cnt
__global__ __launch_bounds__(1024) void k_prep(
    const float* __restrict__ orig, const float* __restrict__ proj,
    const float* __restrict__ vertex, const int* __restrict__ nidx,
    const float* __restrict__ W0, const float* __restrict__ W1, const float* __restrict__ W2,
    ushortT* __restrict__ wpk, ushortT* __restrict__ x0g,
    float* __restrict__ accg, int* __restrict__ cnt)
{
  const int blk = blockIdx.x, t = threadIdx.x;
  if (blk < 512){
    const int lane = t & 63, w = t >> 6;
    const int p = blk*16 + w;                 // row 0..8191
    const int b = p >> 12, n = p & 4095;

    float v0x=vertex[0], v0y=vertex[1], v0z=vertex[2];
    float r  = __fsqrt_rn(fadd(fadd(fmul(v0x,v0x),fmul(v0y,v0y)),fmul(v0z,v0z)));
    float rr = fmul(r,r);
    int j0 = nidx[0];
    float ax=vertex[3*j0], ay=vertex[3*j0+1], az=vertex[3*j0+2];
    float dx=fsub(v0x,ax), dy=fsub(v0y,ay), dz=fsub(v0z,az);
    float t2 = fadd(fadd(fmul(dx,dx),fmul(dy,dy)),fmul(dz,dz));

    const float* ob = orig + (b*19)*NPTS + n;
    float x=ob[0], y=ob[NPTS], z=ob[2*NPTS];
    float nrm = __fsqrt_rn(fadd(fadd(fmul(x,x),fmul(y,y)),fmul(z,z)));
    float s = __fdiv_rn(r,nrm);
    float px=fmul(x,s), py=fmul(y,s), pz=fmul(z,s);

    int first=0, has=0;
    for (int c0=0; c0<N0V; c0+=256){
      int m0=min(c0+lane,N0V-1), m1=min(c0+lane+64,N0V-1),
          m2=min(c0+lane+128,N0V-1), m3=min(c0+lane+192,N0V-1);
      float a0x=vertex[3*m0],a0y=vertex[3*m0+1],a0z=vertex[3*m0+2];
      float a1x=vertex[3*m1],a1y=vertex[3*m1+1],a1z=vertex[3*m1+2];
      float a2x=vertex[3*m2],a2y=vertex[3*m2+1],a2z=vertex[3*m2+2];
      float a3x=vertex[3*m3],a3y=vertex[3*m3+1],a3z=vertex[3*m3+2];
      float v20=fadd(fadd(fmul(a0x,a0x),fmul(a0y,a0y)),fmul(a0z,a0z));
      float v21=fadd(fadd(fmul(a1x,a1x),fmul(a1y,a1y)),fmul(a1z,a1z));
      float v22=fadd(fadd(fmul(a2x,a2x),fmul(a2y,a2y)),fmul(a2z,a2z));
      float v23=fadd(fadd(fmul(a3x,a3x),fmul(a3y,a3y)),fmul(a3z,a3z));
      float d0=fadd(fadd(fmul(px,a0x),fmul(py,a0y)),fmul(pz,a0z));
      float d1=fadd(fadd(fmul(px,a1x),fmul(py,a1y)),fmul(pz,a1z));
      float d2=fadd(fadd(fmul(px,a2x),fmul(py,a2y)),fmul(pz,a2z));
      float d3=fadd(fadd(fmul(px,a3x),fmul(py,a3y)),fmul(pz,a3z));
      bool h0 = (c0+lane    <N0V) && (fsub(fadd(rr,v20),fmul(2.0f,d0)) <= t2);
      bool h1 = (c0+lane+64 <N0V) && (fsub(fadd(rr,v21),fmul(2.0f,d1)) <= t2);
      bool h2 = (c0+lane+128<N0V) && (fsub(fadd(rr,v22),fmul(2.0f,d2)) <= t2);
      bool h3 = (c0+lane+192<N0V) && (fsub(fadd(rr,v23),fmul(2.0f,d3)) <= t2);
      unsigned long long bal;
      if ((bal=__ballot(h0))){ first=c0     +__builtin_ctzll(bal); has=1; break; }
      if ((bal=__ballot(h1))){ first=c0+ 64+__builtin_ctzll(bal); has=1; break; }
      if ((bal=__ballot(h2))){ first=c0+128+__builtin_ctzll(bal); has=1; break; }
      if ((bal=__ballot(h3))){ first=c0+192+__builtin_ctzll(bal); has=1; break; }
    }

    ushortT* row = x0g + (size_t)p*168;
    const float* pb = proj + (long)b*128*N0V;
    #pragma unroll
    for (int k=0;k<3;k++){
      int idx = lane + k*64;
      if (idx < 168){
        float v;
        if (idx < 19)        v = orig[(b*19+idx)*NPTS + n];
        else if (idx < 147)  v = has ? pb[(long)(idx-19)*N0V + first] : 0.0f;
        else                 v = 0.0f;
        row[idx] = f2bf(v);
      }
    }
  } else if (blk < 567){
    int u = (blk-512)*1024 + t;               // 0..56319
    float v;
    if (u < 21504){ int o=u/168, k=u-o*168; v = (k<147)? W0[o*147+k] : 0.f; }
    else if (u < 38912){ int q=u-21504; int o=q/136,k=q-o*136; v=(k<128)? W1[o*128+k]:0.f; }
    else { int q=u-38912; int o=q/136,k=q-o*136; v=(k<128)? W2[o*128+k]:0.f; }
    wpk[u] = f2bf(v);
  } else {
    for (int i = t; i < 3072; i += 1024)      // zero 3*16*256 = 12288 floats
      ((float4*)accg)[i] = make_float4(0.f,0.f,0.f,0.f);
    if (t < 4) cnt[t] = 0;
  }
}

struct Params {
  const ushortT* wpk; const ushortT* x0g;
  const float* b0; const float* g0; const float* be0;
  const float* b1; const float* g1; const float* be1;
  const float* b2; const float* g2; const float* be2;
  float* accg; int* cnt; float* out;
};

// MFMA pair for one wave: 2 row-tiles (rt0, rt0+2) x 1 col-tile
template<int NS, int WSTR>
__device__ __forceinline__ void layer_mm(const ushortT* xa, const ushortT* wt,
    const float* __restrict__ bias, int li, int hi, int rt0, int colg,
    f32x4& accA, f32x4& accB)
{
  accA = (f32x4){0.f,0.f,0.f,0.f};
  accB = (f32x4){0.f,0.f,0.f,0.f};
  const ushortT* wbp = wt + colg*WSTR + hi*8;
  const ushortT* xaA = xa + (rt0*16 + li)*168 + hi*8;
  const ushortT* xaB = xaA + 32*168;
  #pragma unroll
  for (int s=0;s<NS;s++){
    short8 bb = *(const short8*)(wbp + s*32);
    short8 a0 = *(const short8*)(xaA + s*32);
    short8 a1 = *(const short8*)(xaB + s*32);
    accA = __builtin_amdgcn_mfma_f32_16x16x32_bf16(a0, bb, accA, 0,0,0);
    accB = __builtin_amdgcn_mfma_f32_16x16x32_bf16(a1, bb, accB, 0,0,0);
  }
  float bo = bias[colg];
  #pragma unroll
  for (int r=0;r<4;r++){ accA[r]+=bo; accB[r]+=bo; }
}

// R10-VERBATIM stats mechanism: per-wave atomicAdd into 16 slots -> relaxed counter
// barrier -> 16-slot relaxed atomic read-back. (R11's 1-slot variant failed; suspected
// atomic-queue/arrival race under full-grid same-address contention.)
__device__ __forceinline__ void layer_stats(const f32x4& accA, const f32x4& accB,
    float* __restrict__ accL, int* __restrict__ cntp,
    const float* __restrict__ g, const float* __restrict__ be,
    float* red2, float* stS, float* stB, int t, int blk, int lane, int colg)
{
  float s1=0.f, s2=0.f;
  #pragma unroll
  for (int r=0;r<4;r++){
    s1 += accA[r] + accB[r];
    s2 = fmaf(accA[r],accA[r],fmaf(accB[r],accB[r],s2));
  }
  s1 += __shfl_xor(s1,16); s1 += __shfl_xor(s1,32);
  s2 += __shfl_xor(s2,16); s2 += __shfl_xor(s2,32);
  if (lane < 16){
    float* sl = accL + (blk & (SLOTS-1))*256;
    atomicAdd(&sl[colg], s1);
    atomicAdd(&sl[128 + colg], s2);
  }
  __syncthreads();   // vmcnt(0): this block's adds globally performed
  if (t == 0){
    __hip_atomic_fetch_add(cntp, 1, __ATOMIC_RELAXED, __HIP_MEMORY_SCOPE_AGENT);
    while (__hip_atomic_load(cntp, __ATOMIC_RELAXED, __HIP_MEMORY_SCOPE_AGENT) < NBLK)
      __builtin_amdgcn_s_sleep(2);
  }
  __syncthreads();
  if (t < 256){
    float v = 0.f;
    #pragma unroll
    for (int s=0;s<SLOTS;s++)
      v += __hip_atomic_load(&accL[s*256 + t], __ATOMIC_RELAXED, __HIP_MEMORY_SCOPE_AGENT);
    red2[t] = v;
  }
  __syncthreads();
  if (t < 128){
    float S = red2[t], Q = red2[128 + t];
    float mean = S * (1.0f/8192.0f);
    float var  = Q * (1.0f/8192.0f) - mean*mean;
    float inv  = 1.0f / __fsqrt_rn(var + EPSV);
    float sc = g[t]*inv;
    stS[t] = sc;
    stB[t] = be[t] - mean*sc;
  }
  __syncthreads();
}

__global__ __launch_bounds__(1024) void k_fused(Params p)
{
  extern __shared__ __align__(16) char lds[];
  ushortT* wt0 = (ushortT*)lds;               // [128][168] bf16, 43008B
  ushortT* wt1 = (ushortT*)(lds + 43008);     // [128][136] bf16, 34816B
  ushortT* wt2 = (ushortT*)(lds + 77824);     // [128][136] bf16, 34816B
  ushortT* xa  = (ushortT*)(lds + 112640);    // [64][168]  bf16, 21504B
  __shared__ float red2[256];
  __shared__ float stS[128];
  __shared__ float stB[128];

  const int t    = threadIdx.x;
  const int blk  = blockIdx.x;
  const int lane = t & 63;
  const int w    = t >> 6;           // wave 0..15
  const int b    = blk >> 6;
  const int n0   = (blk & 63) * 64;
  const int li   = lane & 15;
  const int hi   = lane >> 4;
  const int rt0  = w >> 3;           // 0..1 -> row tiles rt0, rt0+2
  const int colg = (w & 7)*16 + li;  // output channel

  // stage weights (110 chunks) + this block's x0 tile (21 chunks) via async DMA
  {
    const char* wsrc = (const char*)p.wpk;
    const char* xsrc = (const char*)p.x0g + (size_t)blk*21504;
    for (int i = w; i < 131; i += 16){
      const char* g; char* l;
      if (i < 110){ g = wsrc + (size_t)i*1024;       l = lds + (size_t)i*1024; }
      else        { g = xsrc + (size_t)(i-110)*1024; l = lds + 112640 + (size_t)(i-110)*1024; }
      g += (size_t)lane*16;
      __builtin_amdgcn_global_load_lds(
          (const __attribute__((address_space(1))) void*)g,
          (__attribute__((address_space(3))) void*)l, 16, 0, 0);
    }
  }
  __syncthreads();   // drains all DMA (vmcnt(0) before barrier)

  f32x4 accA, accB;

  // ---- layer 0: K=160 (5 MFMA steps), weights [128][168] ----
  layer_mm<5,168>(xa, wt0, p.b0, li, hi, rt0, colg, accA, accB);
  layer_stats(accA, accB, p.accg,        p.cnt,   p.g0, p.be0, red2, stS, stB, t, blk, lane, colg);
  {
    float ss = stS[colg], sb = stB[colg];
    #pragma unroll
    for (int r=0;r<4;r++){
      int rowA = rt0*16 + hi*4 + r;
      xa[rowA*168 + colg]      = f2bf(fmaxf(fmaf(accA[r], ss, sb), 0.f));
      xa[(rowA+32)*168 + colg] = f2bf(fmaxf(fmaf(accB[r], ss, sb), 0.f));
    }
  }
  __syncthreads();

  // ---- layer 1: K=128 (4 steps), weights [128][136] ----
  layer_mm<4,136>(xa, wt1, p.b1, li, hi, rt0, colg, accA, accB);
  layer_stats(accA, accB, p.accg + 4096, p.cnt+1, p.g1, p.be1, red2, stS, stB, t, blk, lane, colg);
  {
    float ss = stS[colg], sb = stB[colg];
    #pragma unroll
    for (int r=0;r<4;r++){
      int rowA = rt0*16 + hi*4 + r;
      xa[rowA*168 + colg]      = f2bf(fmaxf(fmaf(accA[r], ss, sb), 0.f));
      xa[(rowA+32)*168 + colg] = f2bf(fmaxf(fmaf(accB[r], ss, sb), 0.f));
    }
  }
  __syncthreads();

  // ---- layer 2: K=128 (4 steps), weights [128][136] ----
  layer_mm<4,136>(xa, wt2, p.b2, li, hi, rt0, colg, accA, accB);
  layer_stats(accA, accB, p.accg + 8192, p.cnt+2, p.g2, p.be2, red2, stS, stB, t, blk, lane, colg);
  {
    // final affine+relu -> f32 tile in dead wt0 region [64][132]
    float* ft = (float*)lds;
    float ss = stS[colg], sb = stB[colg];
    #pragma unroll
    for (int r=0;r<4;r++){
      int rowA = rt0*16 + hi*4 + r;
      ft[rowA*132 + colg]      = fmaxf(fmaf(accA[r], ss, sb), 0.f);
      ft[(rowA+32)*132 + colg] = fmaxf(fmaf(accB[r], ss, sb), 0.f);
    }
  }
  __syncthreads();
  {
    const float* ft = (const float*)lds;
    float* ob = p.out + (long)b*128*NPTS + n0;
    #pragma unroll
    for (int it=0; it<2; it++){
      int idx = t + it*1024;
      int oo = idx >> 4, jj = (idx & 15) * 4;
      float4 v;
      v.x = ft[(jj  )*132 + oo];
      v.y = ft[(jj+1)*132 + oo];
      v.z = ft[(jj+2)*132 + oo];
      v.w = ft[(jj+3)*132 + oo];
      *(float4*)(ob + (long)oo*NPTS + jj) = v;
    }
  }
}

extern "C" void kernel_launch(void* const* d_in, const int* in_sizes, int n_in,
                              void* d_out, int out_size, void* d_ws, size_t ws_size,
                              hipStream_t stream)
{
  const float* orig   = (const float*)d_in[0];
  const float* proj   = (const float*)d_in[1];
  const float* vertex = (const float*)d_in[2];
  const int*   nidx   = (const int*)d_in[3];
  const float* W0 = (const float*)d_in[4];
  const float* b0 = (const float*)d_in[5];
  const float* g0 = (const float*)d_in[6];
  const float* be0= (const float*)d_in[7];
  const float* W1 = (const float*)d_in[8];
  const float* b1 = (const float*)d_in[9];
  const float* g1 = (const float*)d_in[10];
  const float* be1= (const float*)d_in[11];
  const float* W2 = (const float*)d_in[12];
  const float* b2 = (const float*)d_in[13];
  const float* g2 = (const float*)d_in[14];
  const float* be2= (const float*)d_in[15];
  float* out = (float*)d_out;

  float*   ws   = (float*)d_ws;
  float*   accg = ws;                          // 3*16*256 = 12288 floats
  int*     cnt  = (int*)(ws + 12288);          // 4 ints (16 floats reserved)
  ushortT* wpk  = (ushortT*)(ws + 12304);      // 56320 bf16 = 28160 floats
  ushortT* x0g  = (ushortT*)(ws + 40464);      // 8192*168 bf16 = 688128 shorts

  hipFuncSetAttribute((const void*)k_fused,
                      hipFuncAttributeMaxDynamicSharedMemorySize, 134144);

  k_prep<<<568, 1024, 0, stream>>>(orig, proj, vertex, nidx, W0, W1, W2,
                                   wpk, x0g, accg, cnt);

  Params p{wpk, x0g, b0, g0, be0, b1, g1, be1, b2, g2, be2, accg, cnt, out};
  void* args[] = {(void*)&p};
  hipLaunchCooperativeKernel((const void*)k_fused, dim3(NBLK), dim3(1024), args, 134144, stream);
}